// Round 5
// baseline (775.434 us; speedup 1.0000x reference)
//
#include <hip/hip_runtime.h>
#include <cstdint>
#include <cstddef>

// SearchTransfer on MI355X (gfx950), fp32.
// B=4, C=64, H=W=64, L=4096, K=9C=576.
//
// Algebra:
//  - lr-patch norm is a positive per-column scalar -> cannot change argmax; dropped.
//  - S[a,b] = sum_{i,j} D[a+d, b+d], D = ref_flat^T * lr_flat (K=64).
//  - E-tile(r1,r2) = x-band of D-tile (register shuffles, R3-validated).
//  - S-tile(t-1+k, t-1) = E(t-2)+E(t-1)+E(t) along diagonal k: fused streaming with
//    running partials P,Q (registers). Only 8B argmax keys leave the kernel.
//
// R4 lesson: default VGPR heuristic (148) spilled the 192-float P/Q/acc state to
// scratch (32MB writes + 37MB reads per dispatch, 24% VALU). Fix: 1-wave blocks +
// __launch_bounds__(64,1) (up to 512 VGPR, no spill through ~450 measured), no
// barriers, and T14 register prefetch of the next tile under the current k-loop.

#define BATCH 4
#define CCH 64
#define LPIX 4096
#define SEG 8
typedef unsigned long long u64;

__device__ __forceinline__ u64 packKey(float v, int idx) {
    unsigned int bits = __float_as_uint(v);
    unsigned int m = (bits & 0x80000000u) ? ~bits : (bits | 0x80000000u);
    // low 32 = ~idx so that larger key == smaller index on equal value
    return ((u64)m << 32) | (unsigned int)(~(unsigned int)idx);
}

// ---- prep: refT[b][p][c] transpose + ssq[b][p] = sum_c ref^2 -------------
__global__ __launch_bounds__(256) void prep_kernel(const float* __restrict__ ref,
                                                   float* __restrict__ refT,
                                                   float* __restrict__ ssq) {
    __shared__ float s[64 * 65];
    __shared__ float part[256];
    int pt = blockIdx.x, b = blockIdx.y, tid = threadIdx.x;
    const float* rb = ref + ((size_t)b * CCH) * LPIX + pt * 64;
    for (int k = 0; k < 16; ++k) {
        int n = tid + 256 * k;           // n = c*64 + p
        int c = n >> 6, p = n & 63;
        s[c * 65 + p] = rb[(size_t)c * LPIX + p];
    }
    __syncthreads();
    {
        int p = tid & 63, g = tid >> 6;
        float acc = 0.f;
        for (int c = g * 16; c < g * 16 + 16; ++c) { float v = s[c * 65 + p]; acc += v * v; }
        part[g * 64 + p] = acc;
    }
    __syncthreads();
    if (tid < 64) {
        float v = part[tid] + part[64 + tid] + part[128 + tid] + part[192 + tid];
        ssq[b * LPIX + pt * 64 + tid] = v;
    }
    float* tb = refT + ((size_t)b * LPIX + pt * 64) * 64;
    for (int k = 0; k < 16; ++k) {
        int n = tid + 256 * k;           // n = p*64 + c
        int p = n >> 6, c = n & 63;
        tb[n] = s[c * 65 + p];
    }
}

// ---- inv[b][p] = 1 / max(sqrt(3x3 box of ssq), 1e-12) --------------------
__global__ __launch_bounds__(256) void invnorm_kernel(const float* __restrict__ ssq,
                                                      float* __restrict__ inv) {
    int t = blockIdx.x * 256 + threadIdx.x;      // over BATCH*LPIX
    int b = t >> 12, p = t & 4095;
    int y = p >> 6, x = p & 63;
    const float* sb = ssq + b * LPIX;
    float n2 = 0.f;
    for (int i = -1; i <= 1; ++i)
        for (int j = -1; j <= 1; ++j) {
            int yy = y + i, xx = x + j;
            if (yy >= 0 && yy < 64 && xx >= 0 && xx < 64) n2 += sb[yy * 64 + xx];
        }
    inv[t] = 1.0f / fmaxf(sqrtf(n2), 1e-12f);
}

// ---- fused diagonal GEMM + band + argmax (v2: no spill, reg prefetch) ----
// One wave per diagonal segment. grid = (127 diagonals, 8 chunks, batch).
__global__ __launch_bounds__(64, 1) void diag_kernel(const float* __restrict__ ref,
                                                     const float* __restrict__ lr,
                                                     const float* __restrict__ inv,
                                                     u64* __restrict__ packed) {
    __shared__ __align__(16) float As[64 * 64];   // [c][x'] full-K A tile (16 KB)
    __shared__ __align__(16) float Bs[64 * 64];   // [c][x]  full-K B tile (16 KB)
    int k = (int)blockIdx.x - 63;
    int b = blockIdx.z;
    int t_lo = k < 0 ? -k : 0;
    int t_hi = 64 - (k > 0 ? k : 0);
    int t0i = t_lo + (int)blockIdx.y * SEG;
    if (t0i >= t_hi) return;
    int t1i = t0i + SEG < t_hi ? t0i + SEG : t_hi;

    const float* refb = ref + (size_t)b * CCH * LPIX;
    const float* lrb  = lr  + (size_t)b * CCH * LPIX;
    const float* invb = inv + b * LPIX;
    u64* pkb = packed + (size_t)b * LPIX;

    int lane = threadIdx.x;
    int rg = lane >> 3, cg = lane & 7;
    bool rgt = rg > 0, rlt = rg < 7, cgt = cg > 0, clt = cg < 7;

    float P[8][8] = {}, Q[8][8] = {};
    float4 ra[16], rb4[16];

    // prefetch helper: clamped tile index (data for invalid t is never used)
    auto prefetch = [&](int t) {
        int tc = t < t_lo ? t_lo : (t >= t_hi ? t_hi - 1 : t);
        const float* Ag = refb + (tc + k) * 64;
        const float* Bg = lrb + tc * 64;
#pragma unroll
        for (int it = 0; it < 16; ++it) {
            int n = it * 64 + lane;      // f4 idx: c = n>>4, q = n&15
            int c = n >> 4, q = n & 15;
            ra[it]  = *(const float4*)&Ag[(size_t)c * LPIX + 4 * q];
            rb4[it] = *(const float4*)&Bg[(size_t)c * LPIX + 4 * q];
        }
    };
    prefetch(t0i - 1);

    for (int t = t0i - 1; t <= t1i; ++t) {
        bool tv = (t >= t_lo) && (t < t_hi);
        bool fin = (t - 1 >= t0i) && (t - 1 < t1i);
        int yprow = (t - 1 + k) << 6;            // S(t-1) row block * 64
        float iv[8], bv[8];
        int bi[8];
        if (fin) {
            float4 iv0 = *(const float4*)&invb[yprow + rg * 8];
            float4 iv1 = *(const float4*)&invb[yprow + rg * 8 + 4];
            iv[0] = iv0.x; iv[1] = iv0.y; iv[2] = iv0.z; iv[3] = iv0.w;
            iv[4] = iv1.x; iv[5] = iv1.y; iv[6] = iv1.z; iv[7] = iv1.w;
#pragma unroll
            for (int j = 0; j < 8; ++j) { bv[j] = -3.4e38f; bi[j] = 0; }
        }
        if (tv) {
            // commit staged tile to LDS (wave-local: no barrier, lgkmcnt only)
#pragma unroll
            for (int it = 0; it < 16; ++it) {
                int n = it * 64 + lane;
                *(float4*)&As[n * 4] = ra[it];
                *(float4*)&Bs[n * 4] = rb4[it];
            }
            // issue next tile's global loads now; latency hides under k-loop
            if (t < t1i) prefetch(t + 1);

            float acc[8][8] = {};
            const float* Ap = As + rg * 8;
            const float* Bp = Bs + cg * 8;
#pragma unroll 4
            for (int kk = 0; kk < 64; ++kk) {
                float4 a0 = *(const float4*)(Ap + kk * 64);
                float4 a1 = *(const float4*)(Ap + kk * 64 + 4);
                float4 b0 = *(const float4*)(Bp + kk * 64);
                float4 b1 = *(const float4*)(Bp + kk * 64 + 4);
                float av[8] = {a0.x, a0.y, a0.z, a0.w, a1.x, a1.y, a1.z, a1.w};
                float bw[8] = {b0.x, b0.y, b0.z, b0.w, b1.x, b1.y, b1.z, b1.w};
#pragma unroll
                for (int i = 0; i < 8; ++i)
#pragma unroll
                    for (int j = 0; j < 8; ++j) acc[i][j] = fmaf(av[i], bw[j], acc[i][j]);
            }
            // x-band epilogue in registers (R3-validated):
            // E[r][c] = D[r-1][c-1] + D[r][c] + D[r+1][c+1]
            float up[7], lf[7], dn[8], rt[8], um, dpc;
#pragma unroll
            for (int q = 0; q < 7; ++q) up[q] = __shfl(acc[7][q], lane - 8, 64);
            um = __shfl(acc[7][7], lane - 9, 64);
#pragma unroll
            for (int q = 0; q < 7; ++q) lf[q] = __shfl(acc[q][7], lane - 1, 64);
#pragma unroll
            for (int q = 1; q < 8; ++q) dn[q] = __shfl(acc[0][q], lane + 8, 64);
            dpc = __shfl(acc[0][0], lane + 9, 64);
#pragma unroll
            for (int q = 1; q < 8; ++q) rt[q] = __shfl(acc[q][0], lane + 1, 64);
#pragma unroll
            for (int i = 0; i < 8; ++i) {
#pragma unroll
                for (int j = 0; j < 8; ++j) {
                    float dm, dpv;
                    if (i >= 1) dm = (j >= 1) ? acc[i - 1][j - 1] : (cgt ? lf[i - 1] : 0.f);
                    else        dm = rgt ? ((j >= 1) ? up[j - 1] : (cgt ? um : 0.f)) : 0.f;
                    if (i <= 6) dpv = (j <= 6) ? acc[i + 1][j + 1] : (clt ? rt[i + 1] : 0.f);
                    else        dpv = rlt ? ((j <= 6) ? dn[j + 1] : (clt ? dpc : 0.f)) : 0.f;
                    float e = dm + acc[i][j] + dpv;
                    float sv = P[i][j] + e;      // completed S(t-1)[rg*8+i][cg*8+j]
                    P[i][j] = Q[i][j] + e;
                    Q[i][j] = e;
                    if (fin) {
                        float v = sv * iv[i];
                        if (v > bv[j]) { bv[j] = v; bi[j] = i; }
                    }
                }
            }
        } else {
            if (t < t1i) prefetch(t + 1);
#pragma unroll
            for (int i = 0; i < 8; ++i)
#pragma unroll
                for (int j = 0; j < 8; ++j) {
                    float sv = P[i][j];
                    P[i][j] = Q[i][j];
                    Q[i][j] = 0.f;
                    if (fin) {
                        float v = sv * iv[i];
                        if (v > bv[j]) { bv[j] = v; bi[j] = i; }
                    }
                }
        }
        if (fin) {
            u64 key[8];
#pragma unroll
            for (int j = 0; j < 8; ++j) key[j] = packKey(bv[j], yprow + rg * 8 + bi[j]);
#pragma unroll
            for (int d = 8; d <= 32; d <<= 1)
#pragma unroll
                for (int j = 0; j < 8; ++j) {
                    u64 o = __shfl_xor(key[j], d, 64);
                    key[j] = key[j] > o ? key[j] : o;
                }
            if (rg == 0) {
                int cb = ((t - 1) << 6) + cg * 8;
#pragma unroll
                for (int j = 0; j < 8; ++j) atomicMax(&pkb[cb + j], key[j]);
            }
        }
    }
}

// ---- gather + fold: one wave per output pixel ----------------------------
__global__ __launch_bounds__(256) void gather_kernel(const u64* __restrict__ packed,
                                                     const float* __restrict__ refT,
                                                     float* __restrict__ Tt) {
    int b = blockIdx.y;
    int wave = threadIdx.x >> 6, lane = threadIdx.x & 63;
    int p = blockIdx.x * 4 + wave;       // 0..4095
    int py = p >> 6, px = p & 63;
    const u64* pk = packed + (size_t)b * LPIX;
    const float* rT = refT + (size_t)b * LPIX * 64;
    float acc = 0.f;
#pragma unroll
    for (int i = 0; i < 3; ++i)
#pragma unroll
        for (int j = 0; j < 3; ++j) {
            int qy = py + 1 - i, qx = px + 1 - j;
            if ((unsigned)qy >= 64u || (unsigned)qx >= 64u) continue;
            int aidx = (int)(~(unsigned int)pk[qy * 64 + qx]);
            int ry = (aidx >> 6) + i - 1, rx = (aidx & 63) + j - 1;
            if ((unsigned)ry >= 64u || (unsigned)rx >= 64u) continue;
            acc += rT[(size_t)(ry * 64 + rx) * 64 + lane];
        }
    Tt[((size_t)b * LPIX + p) * 64 + lane] = acc;
}

// ---- 1x1 conv: z[b][co][p] = w1[co][0:64]*lr + w1[co][64:128]*T + b1 -----
#define XST 36
__global__ __launch_bounds__(256) void conv1_kernel(const float* __restrict__ lr,
                                                    const float* __restrict__ Tt,
                                                    const float* __restrict__ w1,
                                                    const float* __restrict__ b1,
                                                    float* __restrict__ z) {
    __shared__ __align__(16) float xs[128 * XST];
    __shared__ __align__(16) float wsm[64 * 128];
    int pt = blockIdx.x, b = blockIdx.y, tid = threadIdx.x;
    for (int k = 0; k < 8; ++k) {
        int n = tid + 256 * k;           // 2048 float4s of w1
        *(float4*)&wsm[4 * n] = *(const float4*)&w1[4 * n];
    }
    const float* lrb = lr + (size_t)b * CCH * LPIX + pt * 32;
    for (int k = 0; k < 2; ++k) {
        int n = tid + 256 * k;           // 512 f4: c = n>>3, q = n&7
        int c = n >> 3, q = n & 7;
        *(float4*)&xs[c * XST + 4 * q] = *(const float4*)&lrb[(size_t)c * LPIX + 4 * q];
    }
    const float* Tb = Tt + ((size_t)b * LPIX + pt * 32) * 64;
    for (int k = 0; k < 2; ++k) {
        int n = tid + 256 * k;           // 512 f4: p = n>>4, cq = n&15
        int p = n >> 4, cq = n & 15;
        float4 v = *(const float4*)&Tb[p * 64 + 4 * cq];
        xs[(64 + 4 * cq + 0) * XST + p] = v.x;
        xs[(64 + 4 * cq + 1) * XST + p] = v.y;
        xs[(64 + 4 * cq + 2) * XST + p] = v.z;
        xs[(64 + 4 * cq + 3) * XST + p] = v.w;
    }
    __syncthreads();
    int p = tid & 31, g = tid >> 5;      // g: 8 groups of 8 output channels
    float acc[8];
#pragma unroll
    for (int t = 0; t < 8; ++t) acc[t] = b1[g * 8 + t];
    for (int c = 0; c < 128; ++c) {
        float xv = xs[c * XST + p];
#pragma unroll
        for (int t = 0; t < 8; ++t) acc[t] = fmaf(wsm[(g * 8 + t) * 128 + c], xv, acc[t]);
    }
    float* zb = z + (size_t)b * CCH * LPIX + pt * 32;
#pragma unroll
    for (int t = 0; t < 8; ++t) zb[(size_t)(g * 8 + t) * LPIX + p] = acc[t];
}

// ---- depthwise 3x3 + bias + relu -> out ----------------------------------
__global__ __launch_bounds__(256) void dw_kernel(const float* __restrict__ z,
                                                 const float* __restrict__ wd,
                                                 const float* __restrict__ bd,
                                                 float* __restrict__ out) {
    __shared__ __align__(16) float zs[4096];
    int c = blockIdx.x, b = blockIdx.y, tid = threadIdx.x;
    const float* zb = z + ((size_t)b * CCH + c) * LPIX;
    for (int k = 0; k < 4; ++k) {
        int n = tid + 256 * k;
        *(float4*)&zs[4 * n] = *(const float4*)&zb[4 * n];
    }
    __syncthreads();
    float w[9];
#pragma unroll
    for (int t = 0; t < 9; ++t) w[t] = wd[c * 9 + t];
    float bias = bd[c];
    float* ob = out + ((size_t)b * CCH + c) * LPIX;
    for (int s = 0; s < 16; ++s) {
        int p = tid + 256 * s;
        int y = p >> 6, x = p & 63;
        float acc = bias;
#pragma unroll
        for (int i = 0; i < 3; ++i) {
            int yy = y + i - 1;
            if ((unsigned)yy >= 64u) continue;
#pragma unroll
            for (int j = 0; j < 3; ++j) {
                int xx = x + j - 1;
                if ((unsigned)xx >= 64u) continue;
                acc = fmaf(zs[yy * 64 + xx], w[i * 3 + j], acc);
            }
        }
        ob[p] = fmaxf(acc, 0.f);
    }
}

extern "C" void kernel_launch(void* const* d_in, const int* in_sizes, int n_in,
                              void* d_out, int out_size, void* d_ws, size_t ws_size,
                              hipStream_t stream) {
    const float* lr  = (const float*)d_in[0];
    const float* ref = (const float*)d_in[1];
    const float* w1  = (const float*)d_in[2];
    const float* b1  = (const float*)d_in[3];
    const float* wd  = (const float*)d_in[4];
    const float* bd  = (const float*)d_in[5];
    float* out = (float*)d_out;

    float* ws = (float*)d_ws;
    float* refT = ws;                                   // 1,048,576 f
    float* ssq  = refT + (size_t)1048576;               //    16,384 f
    float* inv  = ssq + 16384;                          //    16,384 f
    u64* packed = (u64*)(inv + 16384);                  //    16,384 u64
    float* Tt = (float*)(packed + 16384);               // 1,048,576 f
    float* z  = Tt + (size_t)1048576;                   // 1,048,576 f
    // total ~12.8 MiB of d_ws (no E tensor)

    hipMemsetAsync(packed, 0, (size_t)BATCH * LPIX * sizeof(u64), stream);
    prep_kernel<<<dim3(64, BATCH), 256, 0, stream>>>(ref, refT, ssq);
    invnorm_kernel<<<dim3(64), 256, 0, stream>>>(ssq, inv);
    diag_kernel<<<dim3(127, 8, BATCH), 64, 0, stream>>>(ref, lr, inv, packed);
    gather_kernel<<<dim3(1024, BATCH), 256, 0, stream>>>(packed, refT, Tt);
    conv1_kernel<<<dim3(128, BATCH), 256, 0, stream>>>(lr, Tt, w1, b1, z);
    dw_kernel<<<dim3(64, BATCH), 256, 0, stream>>>(z, wd, bd, out);
}

// Round 6
// 417.754 us; speedup vs baseline: 1.8562x; 1.8562x over previous
//
#include <hip/hip_runtime.h>
#include <cstdint>
#include <cstddef>

// SearchTransfer on MI355X (gfx950), fp32.
// B=4, C=64, H=W=64, L=4096, K=9C=576.
//
// Algebra:
//  - lr-patch norm is a positive per-column scalar -> cannot change argmax; dropped.
//  - S[a,b] = sum_{i,j} D[a+d, b+d], D = ref_flat^T * lr_flat (K=64).
//  - E-tile = x-band of D-tile (register shuffles + LDS boundary-column exchange).
//  - S(t-1) = E(t-2)+E(t-1)+E(t) along each tile-diagonal: streaming ring,
//    P (partial) in registers, Q in LDS. Only 8B argmax keys leave the kernel.
//
// R4/R5 lesson: >128-VGPR designs spilled (allocator gave 140-148 despite
// launch_bounds). v3: col-split tile across 2 waves (acc 8x4 = 32) + Q-ring in
// LDS + operands straight from global (L2-resident, 2 MB/batch) => ~120 live
// VGPRs. XCD swizzle pins each batch to 2 XCDs' L2.

#define BATCH 4
#define CCH 64
#define LPIX 4096
#define SEG2 16
typedef unsigned long long u64;

__device__ __forceinline__ u64 packKey(float v, int idx) {
    unsigned int bits = __float_as_uint(v);
    unsigned int m = (bits & 0x80000000u) ? ~bits : (bits | 0x80000000u);
    // low 32 = ~idx so that larger key == smaller index on equal value
    return ((u64)m << 32) | (unsigned int)(~(unsigned int)idx);
}

// ---- prep: refT[b][p][c] transpose + ssq[b][p] = sum_c ref^2 -------------
__global__ __launch_bounds__(256) void prep_kernel(const float* __restrict__ ref,
                                                   float* __restrict__ refT,
                                                   float* __restrict__ ssq) {
    __shared__ float s[64 * 65];
    __shared__ float part[256];
    int pt = blockIdx.x, b = blockIdx.y, tid = threadIdx.x;
    const float* rb = ref + ((size_t)b * CCH) * LPIX + pt * 64;
    for (int k = 0; k < 16; ++k) {
        int n = tid + 256 * k;           // n = c*64 + p
        int c = n >> 6, p = n & 63;
        s[c * 65 + p] = rb[(size_t)c * LPIX + p];
    }
    __syncthreads();
    {
        int p = tid & 63, g = tid >> 6;
        float acc = 0.f;
        for (int c = g * 16; c < g * 16 + 16; ++c) { float v = s[c * 65 + p]; acc += v * v; }
        part[g * 64 + p] = acc;
    }
    __syncthreads();
    if (tid < 64) {
        float v = part[tid] + part[64 + tid] + part[128 + tid] + part[192 + tid];
        ssq[b * LPIX + pt * 64 + tid] = v;
    }
    float* tb = refT + ((size_t)b * LPIX + pt * 64) * 64;
    for (int k = 0; k < 16; ++k) {
        int n = tid + 256 * k;           // n = p*64 + c
        int p = n >> 6, c = n & 63;
        tb[n] = s[c * 65 + p];
    }
}

// ---- inv[b][p] = 1 / max(sqrt(3x3 box of ssq), 1e-12) --------------------
__global__ __launch_bounds__(256) void invnorm_kernel(const float* __restrict__ ssq,
                                                      float* __restrict__ inv) {
    int t = blockIdx.x * 256 + threadIdx.x;      // over BATCH*LPIX
    int b = t >> 12, p = t & 4095;
    int y = p >> 6, x = p & 63;
    const float* sb = ssq + b * LPIX;
    float n2 = 0.f;
    for (int i = -1; i <= 1; ++i)
        for (int j = -1; j <= 1; ++j) {
            int yy = y + i, xx = x + j;
            if (yy >= 0 && yy < 64 && xx >= 0 && xx < 64) n2 += sb[yy * 64 + xx];
        }
    inv[t] = 1.0f / fmaxf(sqrtf(n2), 1e-12f);
}

// ---- fused diagonal GEMM + band + argmax (v3) ----------------------------
// Flat grid 2032 blocks (XCD-swizzled), 128 threads = 2 waves = 2 col-strips.
__global__ __launch_bounds__(128) void diag_kernel(const float* __restrict__ ref,
                                                   const float* __restrict__ lr,
                                                   const float* __restrict__ inv,
                                                   u64* __restrict__ packed) {
    __shared__ __align__(16) float Qs[2 * 64 * 36];  // per-lane 36-word stride (b128 clean)
    __shared__ float Xc0[66], Xc1[66];               // boundary cols, zero-padded rows

    int id = blockIdx.x;                 // 0..2031
    int xcd = id & 7;
    int b = xcd >> 1;                    // batch pinned to 2 XCDs
    int local = ((id >> 3) << 1) | (xcd & 1);   // 0..507
    int seg = local / 127;
    int kidx = local - seg * 127;
    int k = kidx - 63;
    int t_lo = k < 0 ? -k : 0;
    int t_hi = 64 - (k > 0 ? k : 0);
    int t0 = t_lo + seg * SEG2;
    if (t0 >= t_hi) return;
    int t1 = t0 + SEG2 < t_hi ? t0 + SEG2 : t_hi;

    const float* refb = ref + (size_t)b * CCH * LPIX;
    const float* lrb  = lr  + (size_t)b * CCH * LPIX;
    const float* invb = inv + b * LPIX;
    u64* pkb = packed + (size_t)b * LPIX;

    int tid = threadIdx.x;
    int w = tid >> 6, l = tid & 63;
    int rg = l >> 3, cg = l & 7;
    int r0 = rg * 8;                     // thread's first row (x')
    int S = 32 * w;                      // strip base col (x)

    float4* q4 = (float4*)Qs + (size_t)w * 576 + l * 9;   // 9 f4/lane (36 words)
#pragma unroll
    for (int i = 0; i < 8; ++i) q4[i] = make_float4(0.f, 0.f, 0.f, 0.f);
    if (tid == 0) { Xc0[0] = 0.f; Xc0[65] = 0.f; Xc1[0] = 0.f; Xc1[65] = 0.f; }

    float P[8][4];
#pragma unroll
    for (int i = 0; i < 8; ++i)
#pragma unroll
        for (int j = 0; j < 4; ++j) P[i][j] = 0.f;

    for (int t = t0 - 1; t <= t1; ++t) {
        bool tv = (t >= t_lo) && (t < t_hi);
        bool fin = (t - 1 >= t0) && (t - 1 < t1);
        int yprow = (t - 1 + k) << 6;    // finalized S row-block * 64
        float acc[8][4];
        if (tv) {
#pragma unroll
            for (int i = 0; i < 8; ++i)
#pragma unroll
                for (int j = 0; j < 4; ++j) acc[i][j] = 0.f;
            int r1 = t + k, r2 = t;
            const float* Ap = refb + (size_t)(r1 * 64 + r0);
            const float* Bp = lrb + (size_t)(r2 * 64 + S + cg * 4);
#pragma unroll 8
            for (int kk = 0; kk < 64; ++kk) {
                float4 a0 = *(const float4*)Ap;
                float4 a1 = *(const float4*)(Ap + 4);
                float4 b0 = *(const float4*)Bp;
                Ap += LPIX; Bp += LPIX;
                float av[8] = {a0.x, a0.y, a0.z, a0.w, a1.x, a1.y, a1.z, a1.w};
#pragma unroll
                for (int i = 0; i < 8; ++i) {
                    acc[i][0] = fmaf(av[i], b0.x, acc[i][0]);
                    acc[i][1] = fmaf(av[i], b0.y, acc[i][1]);
                    acc[i][2] = fmaf(av[i], b0.z, acc[i][2]);
                    acc[i][3] = fmaf(av[i], b0.w, acc[i][3]);
                }
            }
            if (w == 0 && cg == 7) {     // export col 31 (D[.][31])
#pragma unroll
                for (int i = 0; i < 8; ++i) Xc0[r0 + i + 1] = acc[i][3];
            }
            if (w == 1 && cg == 0) {     // export col 32 (D[.][32])
#pragma unroll
                for (int i = 0; i < 8; ++i) Xc1[r0 + i + 1] = acc[i][0];
            }
        }
        __syncthreads();

        float bv[4]; int bi[4];
        if (fin) {
#pragma unroll
            for (int j = 0; j < 4; ++j) { bv[j] = -3.4e38f; bi[j] = 0; }
        }

        if (tv) {
            // cross-lane halos (same D values as validated shuffle epilogue)
            float up8[3], um, lf[7], dn8[4], dpc, rt[8];
#pragma unroll
            for (int jj = 0; jj < 3; ++jj) up8[jj] = __shfl(acc[7][jj], l - 8, 64);
            um = __shfl(acc[7][3], l - 9, 64);
#pragma unroll
            for (int ii = 0; ii < 7; ++ii) lf[ii] = __shfl(acc[ii][3], l - 1, 64);
#pragma unroll
            for (int jj = 1; jj < 4; ++jj) dn8[jj] = __shfl(acc[0][jj], l + 8, 64);
            dpc = __shfl(acc[0][0], l + 9, 64);
#pragma unroll
            for (int ii = 1; ii < 8; ++ii) rt[ii] = __shfl(acc[ii][0], l + 1, 64);

#pragma unroll
            for (int i = 0; i < 8; ++i) {
                int r = r0 + i;
                float ivr = fin ? invb[yprow + r] : 0.f;
                float e[4];
#pragma unroll
                for (int j = 0; j < 4; ++j) {
                    float dm;                         // D[r-1][c-1]
                    if (j >= 1) {
                        if (i >= 1) dm = acc[i - 1][j - 1];
                        else dm = (rg > 0) ? up8[j - 1] : 0.f;
                    } else {
                        if (cg > 0) {
                            if (i >= 1) dm = lf[i - 1];
                            else dm = (rg > 0) ? um : 0.f;
                        } else {
                            dm = (w == 1) ? Xc0[r] : 0.f;
                        }
                    }
                    float dp;                         // D[r+1][c+1]
                    if (j <= 2) {
                        if (i <= 6) dp = acc[i + 1][j + 1];
                        else dp = (rg < 7) ? dn8[j + 1] : 0.f;
                    } else {
                        if (cg < 7) {
                            if (i <= 6) dp = rt[i + 1];
                            else dp = (rg < 7) ? dpc : 0.f;
                        } else {
                            dp = (w == 0) ? Xc1[r + 2] : 0.f;
                        }
                    }
                    e[j] = dm + acc[i][j] + dp;
                }
                float4 q = q4[i];
                float qv[4] = {q.x, q.y, q.z, q.w};
                float sv[4];
#pragma unroll
                for (int j = 0; j < 4; ++j) {
                    sv[j] = P[i][j] + e[j];          // completed S(t-1)
                    P[i][j] = qv[j] + e[j];
                }
                q4[i] = make_float4(e[0], e[1], e[2], e[3]);
                if (fin) {
#pragma unroll
                    for (int j = 0; j < 4; ++j) {
                        float v = sv[j] * ivr;
                        if (v > bv[j]) { bv[j] = v; bi[j] = i; }
                    }
                }
            }
        } else {
#pragma unroll
            for (int i = 0; i < 8; ++i) {
                float ivr = fin ? invb[yprow + r0 + i] : 0.f;
                float4 q = q4[i];
                float qv[4] = {q.x, q.y, q.z, q.w};
#pragma unroll
                for (int j = 0; j < 4; ++j) {
                    float sv = P[i][j];
                    P[i][j] = qv[j];
                    if (fin) {
                        float v = sv * ivr;
                        if (v > bv[j]) { bv[j] = v; bi[j] = i; }
                    }
                }
                q4[i] = make_float4(0.f, 0.f, 0.f, 0.f);
            }
        }

        if (fin) {
            u64 key[4];
#pragma unroll
            for (int j = 0; j < 4; ++j) key[j] = packKey(bv[j], yprow + r0 + bi[j]);
#pragma unroll
            for (int d = 8; d <= 32; d <<= 1)
#pragma unroll
                for (int j = 0; j < 4; ++j) {
                    u64 o = __shfl_xor(key[j], d, 64);
                    key[j] = key[j] > o ? key[j] : o;
                }
            if (rg == 0) {               // lanes 0..7 hold col results
                int cb = ((t - 1) << 6) + S + cg * 4;
#pragma unroll
                for (int j = 0; j < 4; ++j) atomicMax(&pkb[cb + j], key[j]);
            }
        }
        __syncthreads();                 // WAR on Xc before next tile
    }
}

// ---- gather + fold: one wave per output pixel ----------------------------
__global__ __launch_bounds__(256) void gather_kernel(const u64* __restrict__ packed,
                                                     const float* __restrict__ refT,
                                                     float* __restrict__ Tt) {
    int b = blockIdx.y;
    int wave = threadIdx.x >> 6, lane = threadIdx.x & 63;
    int p = blockIdx.x * 4 + wave;       // 0..4095
    int py = p >> 6, px = p & 63;
    const u64* pk = packed + (size_t)b * LPIX;
    const float* rT = refT + (size_t)b * LPIX * 64;
    float acc = 0.f;
#pragma unroll
    for (int i = 0; i < 3; ++i)
#pragma unroll
        for (int j = 0; j < 3; ++j) {
            int qy = py + 1 - i, qx = px + 1 - j;
            if ((unsigned)qy >= 64u || (unsigned)qx >= 64u) continue;
            int aidx = (int)(~(unsigned int)pk[qy * 64 + qx]);
            int ry = (aidx >> 6) + i - 1, rx = (aidx & 63) + j - 1;
            if ((unsigned)ry >= 64u || (unsigned)rx >= 64u) continue;
            acc += rT[(size_t)(ry * 64 + rx) * 64 + lane];
        }
    Tt[((size_t)b * LPIX + p) * 64 + lane] = acc;
}

// ---- 1x1 conv: z[b][co][p] = w1[co][0:64]*lr + w1[co][64:128]*T + b1 -----
#define XST 36
__global__ __launch_bounds__(256) void conv1_kernel(const float* __restrict__ lr,
                                                    const float* __restrict__ Tt,
                                                    const float* __restrict__ w1,
                                                    const float* __restrict__ b1,
                                                    float* __restrict__ z) {
    __shared__ __align__(16) float xs[128 * XST];
    __shared__ __align__(16) float wsm[64 * 128];
    int pt = blockIdx.x, b = blockIdx.y, tid = threadIdx.x;
    for (int k = 0; k < 8; ++k) {
        int n = tid + 256 * k;           // 2048 float4s of w1
        *(float4*)&wsm[4 * n] = *(const float4*)&w1[4 * n];
    }
    const float* lrb = lr + (size_t)b * CCH * LPIX + pt * 32;
    for (int k = 0; k < 2; ++k) {
        int n = tid + 256 * k;           // 512 f4: c = n>>3, q = n&7
        int c = n >> 3, q = n & 7;
        *(float4*)&xs[c * XST + 4 * q] = *(const float4*)&lrb[(size_t)c * LPIX + 4 * q];
    }
    const float* Tb = Tt + ((size_t)b * LPIX + pt * 32) * 64;
    for (int k = 0; k < 2; ++k) {
        int n = tid + 256 * k;           // 512 f4: p = n>>4, cq = n&15
        int p = n >> 4, cq = n & 15;
        float4 v = *(const float4*)&Tb[p * 64 + 4 * cq];
        xs[(64 + 4 * cq + 0) * XST + p] = v.x;
        xs[(64 + 4 * cq + 1) * XST + p] = v.y;
        xs[(64 + 4 * cq + 2) * XST + p] = v.z;
        xs[(64 + 4 * cq + 3) * XST + p] = v.w;
    }
    __syncthreads();
    int p = tid & 31, g = tid >> 5;      // g: 8 groups of 8 output channels
    float acc[8];
#pragma unroll
    for (int t = 0; t < 8; ++t) acc[t] = b1[g * 8 + t];
    for (int c = 0; c < 128; ++c) {
        float xv = xs[c * XST + p];
#pragma unroll
        for (int t = 0; t < 8; ++t) acc[t] = fmaf(wsm[(g * 8 + t) * 128 + c], xv, acc[t]);
    }
    float* zb = z + (size_t)b * CCH * LPIX + pt * 32;
#pragma unroll
    for (int t = 0; t < 8; ++t) zb[(size_t)(g * 8 + t) * LPIX + p] = acc[t];
}

// ---- depthwise 3x3 + bias + relu -> out ----------------------------------
__global__ __launch_bounds__(256) void dw_kernel(const float* __restrict__ z,
                                                 const float* __restrict__ wd,
                                                 const float* __restrict__ bd,
                                                 float* __restrict__ out) {
    __shared__ __align__(16) float zs[4096];
    int c = blockIdx.x, b = blockIdx.y, tid = threadIdx.x;
    const float* zb = z + ((size_t)b * CCH + c) * LPIX;
    for (int k = 0; k < 4; ++k) {
        int n = tid + 256 * k;
        *(float4*)&zs[4 * n] = *(const float4*)&zb[4 * n];
    }
    __syncthreads();
    float w[9];
#pragma unroll
    for (int t = 0; t < 9; ++t) w[t] = wd[c * 9 + t];
    float bias = bd[c];
    float* ob = out + ((size_t)b * CCH + c) * LPIX;
    for (int s = 0; s < 16; ++s) {
        int p = tid + 256 * s;
        int y = p >> 6, x = p & 63;
        float acc = bias;
#pragma unroll
        for (int i = 0; i < 3; ++i) {
            int yy = y + i - 1;
            if ((unsigned)yy >= 64u) continue;
#pragma unroll
            for (int j = 0; j < 3; ++j) {
                int xx = x + j - 1;
                if ((unsigned)xx >= 64u) continue;
                acc = fmaf(zs[yy * 64 + xx], w[i * 3 + j], acc);
            }
        }
        ob[p] = fmaxf(acc, 0.f);
    }
}

extern "C" void kernel_launch(void* const* d_in, const int* in_sizes, int n_in,
                              void* d_out, int out_size, void* d_ws, size_t ws_size,
                              hipStream_t stream) {
    const float* lr  = (const float*)d_in[0];
    const float* ref = (const float*)d_in[1];
    const float* w1  = (const float*)d_in[2];
    const float* b1  = (const float*)d_in[3];
    const float* wd  = (const float*)d_in[4];
    const float* bd  = (const float*)d_in[5];
    float* out = (float*)d_out;

    float* ws = (float*)d_ws;
    float* refT = ws;                                   // 1,048,576 f
    float* ssq  = refT + (size_t)1048576;               //    16,384 f
    float* inv  = ssq + 16384;                          //    16,384 f
    u64* packed = (u64*)(inv + 16384);                  //    16,384 u64
    float* Tt = (float*)(packed + 16384);               // 1,048,576 f
    float* z  = Tt + (size_t)1048576;                   // 1,048,576 f
    // total ~12.8 MiB of d_ws (no E tensor)

    hipMemsetAsync(packed, 0, (size_t)BATCH * LPIX * sizeof(u64), stream);
    prep_kernel<<<dim3(64, BATCH), 256, 0, stream>>>(ref, refT, ssq);
    invnorm_kernel<<<dim3(64), 256, 0, stream>>>(ssq, inv);
    diag_kernel<<<dim3(2032), 128, 0, stream>>>(ref, lr, inv, packed);
    gather_kernel<<<dim3(1024, BATCH), 256, 0, stream>>>(packed, refT, Tt);
    conv1_kernel<<<dim3(128, BATCH), 256, 0, stream>>>(lr, Tt, w1, b1, z);
    dw_kernel<<<dim3(64, BATCH), 256, 0, stream>>>(z, wd, bd, out);
}

// Round 7
// 384.797 us; speedup vs baseline: 2.0152x; 1.0856x over previous
//
#include <hip/hip_runtime.h>
#include <cstdint>
#include <cstddef>

// SearchTransfer on MI355X (gfx950), fp32.
// B=4, C=64, H=W=64, L=4096, K=9C=576.
//
// Algebra:
//  - lr-patch norm is a positive per-column scalar -> cannot change argmax; dropped.
//  - S[a,b] = sum_{i,j} D[a+d, b+d], D = ref_flat^T * lr_flat (K=64).
//  - E-tile = x-band of D-tile (register shuffles + LDS boundary-column exchange).
//  - S(t-1) = E(t-2)+E(t-1)+E(t) along each tile-diagonal: streaming ring,
//    P (partial) in registers, Q in LDS. Only 8B argmax keys leave the kernel.
//
// R6 lesson: direct global operand reads + 72 VGPR = latency-bound (39% VALU,
// 21% occ). v4: K-split (BK=32) double-buffered LDS staging via T14 reg->LDS
// (loads issued after barrier, hidden under previous half's FMA loop), balanced
// closed-form segment grid (no empty blocks), launch_bounds(128,3).

#define BATCH 4
#define CCH 64
#define LPIX 4096
#define SEG2 16
typedef unsigned long long u64;

__device__ __forceinline__ u64 packKey(float v, int idx) {
    unsigned int bits = __float_as_uint(v);
    unsigned int m = (bits & 0x80000000u) ? ~bits : (bits | 0x80000000u);
    // low 32 = ~idx so that larger key == smaller index on equal value
    return ((u64)m << 32) | (unsigned int)(~(unsigned int)idx);
}

// ---- prep: refT[b][p][c] transpose + ssq[b][p] = sum_c ref^2 -------------
__global__ __launch_bounds__(256) void prep_kernel(const float* __restrict__ ref,
                                                   float* __restrict__ refT,
                                                   float* __restrict__ ssq) {
    __shared__ float s[64 * 65];
    __shared__ float part[256];
    int pt = blockIdx.x, b = blockIdx.y, tid = threadIdx.x;
    const float* rb = ref + ((size_t)b * CCH) * LPIX + pt * 64;
    for (int k = 0; k < 16; ++k) {
        int n = tid + 256 * k;           // n = c*64 + p
        int c = n >> 6, p = n & 63;
        s[c * 65 + p] = rb[(size_t)c * LPIX + p];
    }
    __syncthreads();
    {
        int p = tid & 63, g = tid >> 6;
        float acc = 0.f;
        for (int c = g * 16; c < g * 16 + 16; ++c) { float v = s[c * 65 + p]; acc += v * v; }
        part[g * 64 + p] = acc;
    }
    __syncthreads();
    if (tid < 64) {
        float v = part[tid] + part[64 + tid] + part[128 + tid] + part[192 + tid];
        ssq[b * LPIX + pt * 64 + tid] = v;
    }
    float* tb = refT + ((size_t)b * LPIX + pt * 64) * 64;
    for (int k = 0; k < 16; ++k) {
        int n = tid + 256 * k;           // n = p*64 + c
        int p = n >> 6, c = n & 63;
        tb[n] = s[c * 65 + p];
    }
}

// ---- inv[b][p] = 1 / max(sqrt(3x3 box of ssq), 1e-12) --------------------
__global__ __launch_bounds__(256) void invnorm_kernel(const float* __restrict__ ssq,
                                                      float* __restrict__ inv) {
    int t = blockIdx.x * 256 + threadIdx.x;      // over BATCH*LPIX
    int b = t >> 12, p = t & 4095;
    int y = p >> 6, x = p & 63;
    const float* sb = ssq + b * LPIX;
    float n2 = 0.f;
    for (int i = -1; i <= 1; ++i)
        for (int j = -1; j <= 1; ++j) {
            int yy = y + i, xx = x + j;
            if (yy >= 0 && yy < 64 && xx >= 0 && xx < 64) n2 += sb[yy * 64 + xx];
        }
    inv[t] = 1.0f / fmaxf(sqrtf(n2), 1e-12f);
}

// ---- fused diagonal GEMM + band + argmax (v4: LDS-staged, balanced grid) --
// grid = (316 segments, batch); block = 128 threads = 2 waves = 2 col-strips.
#define STAGE_LOAD(T, H) do {                                                  \
    int tc_ = (T); tc_ = tc_ < t_lo ? t_lo : (tc_ >= t_hi ? t_hi - 1 : tc_);   \
    const float* Ag_ = refb + (size_t)((H) * 32) * LPIX + (tc_ + k) * 64;      \
    const float* Bg_ = lrb  + (size_t)((H) * 32) * LPIX + tc_ * 64;            \
    int c_ = tid >> 4, q_ = (tid & 15) * 4;                                    \
    sa0 = *(const float4*)&Ag_[(size_t)c_ * LPIX + q_];                        \
    sb0 = *(const float4*)&Bg_[(size_t)c_ * LPIX + q_];                        \
    sa1 = *(const float4*)&Ag_[(size_t)(c_ + 8) * LPIX + q_];                  \
    sb1 = *(const float4*)&Bg_[(size_t)(c_ + 8) * LPIX + q_];                  \
    sa2 = *(const float4*)&Ag_[(size_t)(c_ + 16) * LPIX + q_];                 \
    sb2 = *(const float4*)&Bg_[(size_t)(c_ + 16) * LPIX + q_];                 \
    sa3 = *(const float4*)&Ag_[(size_t)(c_ + 24) * LPIX + q_];                 \
    sb3 = *(const float4*)&Bg_[(size_t)(c_ + 24) * LPIX + q_];                 \
} while (0)

#define STAGE_COMMIT(P) do {                                                   \
    float* Ad_ = As + (P) * 2048 + 4 * tid;                                    \
    float* Bd_ = Bs + (P) * 2048 + 4 * tid;                                    \
    *(float4*)&Ad_[0]    = sa0;  *(float4*)&Bd_[0]    = sb0;                   \
    *(float4*)&Ad_[512]  = sa1;  *(float4*)&Bd_[512]  = sb1;                   \
    *(float4*)&Ad_[1024] = sa2;  *(float4*)&Bd_[1024] = sb2;                   \
    *(float4*)&Ad_[1536] = sa3;  *(float4*)&Bd_[1536] = sb3;                   \
} while (0)

#define ACC_HALF(P) do {                                                       \
    const float* Ap_ = As + (P) * 2048 + rg * 8;                               \
    const float* Bp_ = Bs + (P) * 2048 + S + cg * 4;                           \
    _Pragma("unroll 4")                                                        \
    for (int kk = 0; kk < 32; ++kk) {                                          \
        float4 a0 = *(const float4*)(Ap_ + kk * 64);                           \
        float4 a1 = *(const float4*)(Ap_ + kk * 64 + 4);                       \
        float4 b0 = *(const float4*)(Bp_ + kk * 64);                           \
        float av[8] = {a0.x, a0.y, a0.z, a0.w, a1.x, a1.y, a1.z, a1.w};        \
        _Pragma("unroll")                                                      \
        for (int i = 0; i < 8; ++i) {                                          \
            acc[i][0] = fmaf(av[i], b0.x, acc[i][0]);                          \
            acc[i][1] = fmaf(av[i], b0.y, acc[i][1]);                          \
            acc[i][2] = fmaf(av[i], b0.z, acc[i][2]);                          \
            acc[i][3] = fmaf(av[i], b0.w, acc[i][3]);                          \
        }                                                                      \
    }                                                                          \
} while (0)

__global__ __launch_bounds__(128, 3) void diag_kernel(const float* __restrict__ ref,
                                                      const float* __restrict__ lr,
                                                      const float* __restrict__ inv,
                                                      u64* __restrict__ packed) {
    __shared__ __align__(16) float As[2 * 2048];     // K-split double buffer (8 KB ea)
    __shared__ __align__(16) float Bs[2 * 2048];
    __shared__ __align__(16) float Qs[2 * 64 * 36];  // ring Q, per-lane 36-word stride
    __shared__ float Xc0[66], Xc1[66];               // boundary cols, zero-padded rows

    int sid = blockIdx.x, b = blockIdx.y;
    // closed-form sid -> (k, seg): groups by segments-per-diagonal
    int k, seg;
    if (sid < 124)      { int d = sid;       seg = d & 3;  d >>= 2; k = d - 15; }
    else if (sid < 220) { int e = sid - 124; int d = e / 3; seg = e - d * 3;
                          k = (d < 16) ? 16 + d : -d; }
    else if (sid < 284) { int f = sid - 220; int d = f >> 1; seg = f & 1;
                          k = (d < 16) ? 32 + d : -(16 + d); }
    else                { int d = sid - 284; seg = 0;
                          k = (d < 16) ? 48 + d : -(32 + d); }
    int t_lo = k < 0 ? -k : 0;
    int t_hi = 64 - (k > 0 ? k : 0);
    int t0 = t_lo + seg * SEG2;
    int t1 = t0 + SEG2 < t_hi ? t0 + SEG2 : t_hi;

    const float* refb = ref + (size_t)b * CCH * LPIX;
    const float* lrb  = lr  + (size_t)b * CCH * LPIX;
    const float* invb = inv + b * LPIX;
    u64* pkb = packed + (size_t)b * LPIX;

    int tid = threadIdx.x;
    int w = tid >> 6, l = tid & 63;
    int rg = l >> 3, cg = l & 7;
    int r0 = rg * 8;                     // thread's first row (x')
    int S = 32 * w;                      // strip base col (x)

    float4* q4 = (float4*)Qs + (size_t)w * 576 + l * 9;   // 9 f4/lane (36 words)
#pragma unroll
    for (int i = 0; i < 8; ++i) q4[i] = make_float4(0.f, 0.f, 0.f, 0.f);
    if (tid == 0) { Xc0[0] = 0.f; Xc0[65] = 0.f; Xc1[0] = 0.f; Xc1[65] = 0.f; }

    float P[8][4];
#pragma unroll
    for (int i = 0; i < 8; ++i)
#pragma unroll
        for (int j = 0; j < 4; ++j) P[i][j] = 0.f;

    float4 sa0, sa1, sa2, sa3, sb0, sb1, sb2, sb3;
    int p = 0;
    STAGE_LOAD(t0 - 1, 0);

    for (int t = t0 - 1; t <= t1; ++t) {
        bool tv = (t >= t_lo) && (t < t_hi);
        bool fin = (t - 1 >= t0) && (t - 1 < t1);
        int yprow = (t - 1 + k) << 6;    // finalized S row-block * 64
        float acc[8][4];
        // ---- half 0: commit staged regs, issue half-1 loads, compute ----
        STAGE_COMMIT(p);
        STAGE_LOAD(t, 1);
        __syncthreads();
        if (tv) {
#pragma unroll
            for (int i = 0; i < 8; ++i)
#pragma unroll
                for (int j = 0; j < 4; ++j) acc[i][j] = 0.f;
            ACC_HALF(p);
        }
        p ^= 1;
        // ---- half 1: commit, issue next tile's half-0 loads, compute ----
        STAGE_COMMIT(p);
        STAGE_LOAD(t + 1, 0);            // clamped at t1; kept uniform
        __syncthreads();
        if (tv) {
            ACC_HALF(p);
            if (w == 0 && cg == 7) {     // export col 31 (D[.][31])
#pragma unroll
                for (int i = 0; i < 8; ++i) Xc0[r0 + i + 1] = acc[i][3];
            }
            if (w == 1 && cg == 0) {     // export col 32 (D[.][32])
#pragma unroll
                for (int i = 0; i < 8; ++i) Xc1[r0 + i + 1] = acc[i][0];
            }
        }
        p ^= 1;
        __syncthreads();

        float bv[4]; int bi[4];
        if (fin) {
#pragma unroll
            for (int j = 0; j < 4; ++j) { bv[j] = -3.4e38f; bi[j] = 0; }
        }

        if (tv) {
            // cross-lane halos (same D values as validated shuffle epilogue)
            float up8[3], um, lf[7], dn8[4], dpc, rt[8];
#pragma unroll
            for (int jj = 0; jj < 3; ++jj) up8[jj] = __shfl(acc[7][jj], l - 8, 64);
            um = __shfl(acc[7][3], l - 9, 64);
#pragma unroll
            for (int ii = 0; ii < 7; ++ii) lf[ii] = __shfl(acc[ii][3], l - 1, 64);
#pragma unroll
            for (int jj = 1; jj < 4; ++jj) dn8[jj] = __shfl(acc[0][jj], l + 8, 64);
            dpc = __shfl(acc[0][0], l + 9, 64);
#pragma unroll
            for (int ii = 1; ii < 8; ++ii) rt[ii] = __shfl(acc[ii][0], l + 1, 64);

#pragma unroll
            for (int i = 0; i < 8; ++i) {
                int r = r0 + i;
                float ivr = fin ? invb[yprow + r] : 0.f;
                float e[4];
#pragma unroll
                for (int j = 0; j < 4; ++j) {
                    float dm;                         // D[r-1][c-1]
                    if (j >= 1) {
                        if (i >= 1) dm = acc[i - 1][j - 1];
                        else dm = (rg > 0) ? up8[j - 1] : 0.f;
                    } else {
                        if (cg > 0) {
                            if (i >= 1) dm = lf[i - 1];
                            else dm = (rg > 0) ? um : 0.f;
                        } else {
                            dm = (w == 1) ? Xc0[r] : 0.f;
                        }
                    }
                    float dp;                         // D[r+1][c+1]
                    if (j <= 2) {
                        if (i <= 6) dp = acc[i + 1][j + 1];
                        else dp = (rg < 7) ? dn8[j + 1] : 0.f;
                    } else {
                        if (cg < 7) {
                            if (i <= 6) dp = rt[i + 1];
                            else dp = (rg < 7) ? dpc : 0.f;
                        } else {
                            dp = (w == 0) ? Xc1[r + 2] : 0.f;
                        }
                    }
                    e[j] = dm + acc[i][j] + dp;
                }
                float4 q = q4[i];
                float qv[4] = {q.x, q.y, q.z, q.w};
                float sv[4];
#pragma unroll
                for (int j = 0; j < 4; ++j) {
                    sv[j] = P[i][j] + e[j];          // completed S(t-1)
                    P[i][j] = qv[j] + e[j];
                }
                q4[i] = make_float4(e[0], e[1], e[2], e[3]);
                if (fin) {
#pragma unroll
                    for (int j = 0; j < 4; ++j) {
                        float v = sv[j] * ivr;
                        if (v > bv[j]) { bv[j] = v; bi[j] = i; }
                    }
                }
            }
        } else {
#pragma unroll
            for (int i = 0; i < 8; ++i) {
                float ivr = fin ? invb[yprow + r0 + i] : 0.f;
                float4 q = q4[i];
                float qv[4] = {q.x, q.y, q.z, q.w};
#pragma unroll
                for (int j = 0; j < 4; ++j) {
                    float sv = P[i][j];
                    P[i][j] = qv[j];
                    if (fin) {
                        float v = sv * ivr;
                        if (v > bv[j]) { bv[j] = v; bi[j] = i; }
                    }
                }
                q4[i] = make_float4(0.f, 0.f, 0.f, 0.f);
            }
        }

        if (fin) {
            u64 key[4];
#pragma unroll
            for (int j = 0; j < 4; ++j) key[j] = packKey(bv[j], yprow + r0 + bi[j]);
#pragma unroll
            for (int d = 8; d <= 32; d <<= 1)
#pragma unroll
                for (int j = 0; j < 4; ++j) {
                    u64 o = __shfl_xor(key[j], d, 64);
                    key[j] = key[j] > o ? key[j] : o;
                }
            if (rg == 0) {               // lanes 0..7 hold col results
                int cb = ((t - 1) << 6) + S + cg * 4;
#pragma unroll
                for (int j = 0; j < 4; ++j) atomicMax(&pkb[cb + j], key[j]);
            }
        }
        __syncthreads();                 // Xc WAR before next tile
    }
}

// ---- gather + fold: one wave per output pixel ----------------------------
__global__ __launch_bounds__(256) void gather_kernel(const u64* __restrict__ packed,
                                                     const float* __restrict__ refT,
                                                     float* __restrict__ Tt) {
    int b = blockIdx.y;
    int wave = threadIdx.x >> 6, lane = threadIdx.x & 63;
    int p = blockIdx.x * 4 + wave;       // 0..4095
    int py = p >> 6, px = p & 63;
    const u64* pk = packed + (size_t)b * LPIX;
    const float* rT = refT + (size_t)b * LPIX * 64;
    float acc = 0.f;
#pragma unroll
    for (int i = 0; i < 3; ++i)
#pragma unroll
        for (int j = 0; j < 3; ++j) {
            int qy = py + 1 - i, qx = px + 1 - j;
            if ((unsigned)qy >= 64u || (unsigned)qx >= 64u) continue;
            int aidx = (int)(~(unsigned int)pk[qy * 64 + qx]);
            int ry = (aidx >> 6) + i - 1, rx = (aidx & 63) + j - 1;
            if ((unsigned)ry >= 64u || (unsigned)rx >= 64u) continue;
            acc += rT[(size_t)(ry * 64 + rx) * 64 + lane];
        }
    Tt[((size_t)b * LPIX + p) * 64 + lane] = acc;
}

// ---- 1x1 conv: z[b][co][p] = w1[co][0:64]*lr + w1[co][64:128]*T + b1 -----
#define XST 36
__global__ __launch_bounds__(256) void conv1_kernel(const float* __restrict__ lr,
                                                    const float* __restrict__ Tt,
                                                    const float* __restrict__ w1,
                                                    const float* __restrict__ b1,
                                                    float* __restrict__ z) {
    __shared__ __align__(16) float xs[128 * XST];
    __shared__ __align__(16) float wsm[64 * 128];
    int pt = blockIdx.x, b = blockIdx.y, tid = threadIdx.x;
    for (int k = 0; k < 8; ++k) {
        int n = tid + 256 * k;           // 2048 float4s of w1
        *(float4*)&wsm[4 * n] = *(const float4*)&w1[4 * n];
    }
    const float* lrb = lr + (size_t)b * CCH * LPIX + pt * 32;
    for (int k = 0; k < 2; ++k) {
        int n = tid + 256 * k;           // 512 f4: c = n>>3, q = n&7
        int c = n >> 3, q = n & 7;
        *(float4*)&xs[c * XST + 4 * q] = *(const float4*)&lrb[(size_t)c * LPIX + 4 * q];
    }
    const float* Tb = Tt + ((size_t)b * LPIX + pt * 32) * 64;
    for (int k = 0; k < 2; ++k) {
        int n = tid + 256 * k;           // 512 f4: p = n>>4, cq = n&15
        int p = n >> 4, cq = n & 15;
        float4 v = *(const float4*)&Tb[p * 64 + 4 * cq];
        xs[(64 + 4 * cq + 0) * XST + p] = v.x;
        xs[(64 + 4 * cq + 1) * XST + p] = v.y;
        xs[(64 + 4 * cq + 2) * XST + p] = v.z;
        xs[(64 + 4 * cq + 3) * XST + p] = v.w;
    }
    __syncthreads();
    int p = tid & 31, g = tid >> 5;      // g: 8 groups of 8 output channels
    float acc[8];
#pragma unroll
    for (int t = 0; t < 8; ++t) acc[t] = b1[g * 8 + t];
    for (int c = 0; c < 128; ++c) {
        float xv = xs[c * XST + p];
#pragma unroll
        for (int t = 0; t < 8; ++t) acc[t] = fmaf(wsm[(g * 8 + t) * 128 + c], xv, acc[t]);
    }
    float* zb = z + (size_t)b * CCH * LPIX + pt * 32;
#pragma unroll
    for (int t = 0; t < 8; ++t) zb[(size_t)(g * 8 + t) * LPIX + p] = acc[t];
}

// ---- depthwise 3x3 + bias + relu -> out ----------------------------------
__global__ __launch_bounds__(256) void dw_kernel(const float* __restrict__ z,
                                                 const float* __restrict__ wd,
                                                 const float* __restrict__ bd,
                                                 float* __restrict__ out) {
    __shared__ __align__(16) float zs[4096];
    int c = blockIdx.x, b = blockIdx.y, tid = threadIdx.x;
    const float* zb = z + ((size_t)b * CCH + c) * LPIX;
    for (int k = 0; k < 4; ++k) {
        int n = tid + 256 * k;
        *(float4*)&zs[4 * n] = *(const float4*)&zb[4 * n];
    }
    __syncthreads();
    float w[9];
#pragma unroll
    for (int t = 0; t < 9; ++t) w[t] = wd[c * 9 + t];
    float bias = bd[c];
    float* ob = out + ((size_t)b * CCH + c) * LPIX;
    for (int s = 0; s < 16; ++s) {
        int p = tid + 256 * s;
        int y = p >> 6, x = p & 63;
        float acc = bias;
#pragma unroll
        for (int i = 0; i < 3; ++i) {
            int yy = y + i - 1;
            if ((unsigned)yy >= 64u) continue;
#pragma unroll
            for (int j = 0; j < 3; ++j) {
                int xx = x + j - 1;
                if ((unsigned)xx >= 64u) continue;
                acc = fmaf(zs[yy * 64 + xx], w[i * 3 + j], acc);
            }
        }
        ob[p] = fmaxf(acc, 0.f);
    }
}

extern "C" void kernel_launch(void* const* d_in, const int* in_sizes, int n_in,
                              void* d_out, int out_size, void* d_ws, size_t ws_size,
                              hipStream_t stream) {
    const float* lr  = (const float*)d_in[0];
    const float* ref = (const float*)d_in[1];
    const float* w1  = (const float*)d_in[2];
    const float* b1  = (const float*)d_in[3];
    const float* wd  = (const float*)d_in[4];
    const float* bd  = (const float*)d_in[5];
    float* out = (float*)d_out;

    float* ws = (float*)d_ws;
    float* refT = ws;                                   // 1,048,576 f
    float* ssq  = refT + (size_t)1048576;               //    16,384 f
    float* inv  = ssq + 16384;                          //    16,384 f
    u64* packed = (u64*)(inv + 16384);                  //    16,384 u64
    float* Tt = (float*)(packed + 16384);               // 1,048,576 f
    float* z  = Tt + (size_t)1048576;                   // 1,048,576 f
    // total ~12.8 MiB of d_ws (no E tensor)

    hipMemsetAsync(packed, 0, (size_t)BATCH * LPIX * sizeof(u64), stream);
    prep_kernel<<<dim3(64, BATCH), 256, 0, stream>>>(ref, refT, ssq);
    invnorm_kernel<<<dim3(64), 256, 0, stream>>>(ssq, inv);
    diag_kernel<<<dim3(316, BATCH), 128, 0, stream>>>(ref, lr, inv, packed);
    gather_kernel<<<dim3(1024, BATCH), 256, 0, stream>>>(packed, refT, Tt);
    conv1_kernel<<<dim3(128, BATCH), 256, 0, stream>>>(lr, Tt, w1, b1, z);
    dw_kernel<<<dim3(64, BATCH), 256, 0, stream>>>(z, wd, bd, out);
}

// Round 8
// 312.314 us; speedup vs baseline: 2.4829x; 1.2321x over previous
//
#include <hip/hip_runtime.h>
#include <cstdint>
#include <cstddef>

// SearchTransfer on MI355X (gfx950), fp32.
// B=4, C=64, H=W=64, L=4096, K=9C=576.
//
// Algebra:
//  - lr-patch norm is a positive per-column scalar -> cannot change argmax; dropped.
//  - S[a,b] = sum_{i,j} D[a+d, b+d], D = ref_flat^T * lr_flat (K=64).
//  - E-tile(r1,r2) = x-band of D-tile (register shuffles, R3-validated).
//  - S-tile(y',y) = E(y'-1,y-1)+E(y',y)+E(y'+1,y+1): band kernel streams
//    tile-diagonals with a register ring (R2-validated).
//
// R4-R7 lesson: fully-fused diagonal streaming is structurally latency-bound
// (2-wave blocks, barrier-per-tile, <=21% occ, best 373us). R2/R3's
// materialized-E pipeline was WRITE-bound (64 MiB/batch at 1.45 TB/s, 30% occ).
// v8: revert to validated gemmE+band, run NB batches CONCURRENTLY (blockIdx.z,
// NB from ws_size) + non-temporal E stores to lift the write stream toward the
// ~3 TB/s streaming ceiling. Arithmetic identical -> bit-identical output.

#define BATCH 4
#define CCH 64
#define LPIX 4096
typedef unsigned long long u64;
typedef float f4 __attribute__((ext_vector_type(4)));

__device__ __forceinline__ u64 packKey(float v, int idx) {
    unsigned int bits = __float_as_uint(v);
    unsigned int m = (bits & 0x80000000u) ? ~bits : (bits | 0x80000000u);
    // low 32 = ~idx so that larger key == smaller index on equal value
    return ((u64)m << 32) | (unsigned int)(~(unsigned int)idx);
}

// ---- prep: refT[b][p][c] transpose + ssq[b][p] = sum_c ref^2 -------------
__global__ __launch_bounds__(256) void prep_kernel(const float* __restrict__ ref,
                                                   float* __restrict__ refT,
                                                   float* __restrict__ ssq) {
    __shared__ float s[64 * 65];
    __shared__ float part[256];
    int pt = blockIdx.x, b = blockIdx.y, tid = threadIdx.x;
    const float* rb = ref + ((size_t)b * CCH) * LPIX + pt * 64;
    for (int k = 0; k < 16; ++k) {
        int n = tid + 256 * k;           // n = c*64 + p
        int c = n >> 6, p = n & 63;
        s[c * 65 + p] = rb[(size_t)c * LPIX + p];
    }
    __syncthreads();
    {
        int p = tid & 63, g = tid >> 6;
        float acc = 0.f;
        for (int c = g * 16; c < g * 16 + 16; ++c) { float v = s[c * 65 + p]; acc += v * v; }
        part[g * 64 + p] = acc;
    }
    __syncthreads();
    if (tid < 64) {
        float v = part[tid] + part[64 + tid] + part[128 + tid] + part[192 + tid];
        ssq[b * LPIX + pt * 64 + tid] = v;
    }
    float* tb = refT + ((size_t)b * LPIX + pt * 64) * 64;
    for (int k = 0; k < 16; ++k) {
        int n = tid + 256 * k;           // n = p*64 + c
        int p = n >> 6, c = n & 63;
        tb[n] = s[c * 65 + p];
    }
}

// ---- inv[b][p] = 1 / max(sqrt(3x3 box of ssq), 1e-12) --------------------
__global__ __launch_bounds__(256) void invnorm_kernel(const float* __restrict__ ssq,
                                                      float* __restrict__ inv) {
    int t = blockIdx.x * 256 + threadIdx.x;      // over BATCH*LPIX
    int b = t >> 12, p = t & 4095;
    int y = p >> 6, x = p & 63;
    const float* sb = ssq + b * LPIX;
    float n2 = 0.f;
    for (int i = -1; i <= 1; ++i)
        for (int j = -1; j <= 1; ++j) {
            int yy = y + i, xx = x + j;
            if (yy >= 0 && yy < 64 && xx >= 0 && xx < 64) n2 += sb[yy * 64 + xx];
        }
    inv[t] = 1.0f / fmaxf(sqrtf(n2), 1e-12f);
}

// ---- GEMM + x-band epilogue: one wave per 64x64 E-tile (R3-validated) ----
// D[x'][x] = sum_c ref[c,r1,x']*lr[c,r2,x]; E[x'][x] = D[x'-1][x-1]+D[x'][x]+D[x'+1][x+1]
__global__ __launch_bounds__(256, 2) void gemmE_kernel(const float* __restrict__ ref,
                                                       const float* __restrict__ lr,
                                                       float* __restrict__ E) {
    __shared__ __align__(16) float As[2 * 4096];   // [h][c][m], m = x' of tile r1=2by+h
    __shared__ __align__(16) float Bs[2 * 4096];   // [h][c][x], tile r2=2bx+h
    int bx = blockIdx.x, by = blockIdx.y, b = blockIdx.z, tid = threadIdx.x;
    const float* Ab = ref + (size_t)b * CCH * LPIX;
    const float* Bb = lr + (size_t)b * CCH * LPIX;
#pragma unroll
    for (int kk = 0; kk < 8; ++kk) {
        int n = tid + 256 * kk;          // 2048 f4: h = n>>10, c = (n>>4)&63, q = n&15
        int h = n >> 10, c = (n >> 4) & 63, q = n & 15;
        *(float4*)&As[h * 4096 + c * 64 + 4 * q] =
            *(const float4*)&Ab[(size_t)c * LPIX + (2 * by + h) * 64 + 4 * q];
        *(float4*)&Bs[h * 4096 + c * 64 + 4 * q] =
            *(const float4*)&Bb[(size_t)c * LPIX + (2 * bx + h) * 64 + 4 * q];
    }
    __syncthreads();
    int w = tid >> 6, lane = tid & 63, rg = lane >> 3, cg = lane & 7;
    const float* Ap = As + (w >> 1) * 4096 + rg * 8;
    const float* Bp = Bs + (w & 1) * 4096 + cg * 8;
    float acc[8][8] = {};
#pragma unroll 4
    for (int k = 0; k < 64; ++k) {
        float4 a0 = *(const float4*)(Ap + k * 64);
        float4 a1 = *(const float4*)(Ap + k * 64 + 4);
        float4 b0 = *(const float4*)(Bp + k * 64);
        float4 b1 = *(const float4*)(Bp + k * 64 + 4);
        float av[8] = {a0.x, a0.y, a0.z, a0.w, a1.x, a1.y, a1.z, a1.w};
        float bv[8] = {b0.x, b0.y, b0.z, b0.w, b1.x, b1.y, b1.z, b1.w};
#pragma unroll
        for (int i = 0; i < 8; ++i)
#pragma unroll
            for (int j = 0; j < 8; ++j) acc[i][j] = fmaf(av[i], bv[j], acc[i][j]);
    }
    // x-band epilogue in registers: E[r][c] = D[r-1][c-1] + D[r][c] + D[r+1][c+1]
    float up[7], lf[7], dn[8], rt[8], um, dpc;
#pragma unroll
    for (int t = 0; t < 7; ++t) up[t] = __shfl(acc[7][t], lane - 8, 64);
    um = __shfl(acc[7][7], lane - 9, 64);
#pragma unroll
    for (int t = 0; t < 7; ++t) lf[t] = __shfl(acc[t][7], lane - 1, 64);
#pragma unroll
    for (int t = 1; t < 8; ++t) dn[t] = __shfl(acc[0][t], lane + 8, 64);
    dpc = __shfl(acc[0][0], lane + 9, 64);
#pragma unroll
    for (int t = 1; t < 8; ++t) rt[t] = __shfl(acc[t][0], lane + 1, 64);

    int r1 = 2 * by + (w >> 1), r2 = 2 * bx + (w & 1);
    float* Et = E + ((size_t)b << 24) + ((size_t)((r1 << 6) + r2) << 12) + (rg * 8) * 64 + cg * 8;
    bool rgt = rg > 0, rlt = rg < 7, cgt = cg > 0, clt = cg < 7;
#pragma unroll
    for (int i = 0; i < 8; ++i) {
        float e[8];
#pragma unroll
        for (int j = 0; j < 8; ++j) {
            float dm, dpv;
            if (i >= 1) dm = (j >= 1) ? acc[i - 1][j - 1] : (cgt ? lf[i - 1] : 0.f);
            else        dm = rgt ? ((j >= 1) ? up[j - 1] : (cgt ? um : 0.f)) : 0.f;
            if (i <= 6) dpv = (j <= 6) ? acc[i + 1][j + 1] : (clt ? rt[i + 1] : 0.f);
            else        dpv = rlt ? ((j <= 6) ? dn[j + 1] : (clt ? dpc : 0.f)) : 0.f;
            e[j] = dm + acc[i][j] + dpv;
        }
        f4 o0 = {e[0], e[1], e[2], e[3]};
        f4 o1 = {e[4], e[5], e[6], e[7]};
        __builtin_nontemporal_store(o0, (f4*)(Et + i * 64));      // nt: write-once stream
        __builtin_nontemporal_store(o1, (f4*)(Et + i * 64 + 4));
    }
}

// ---- band: diagonal-segment sweep, register ring of 3 E-tiles (R2) -------
// block (bx=segment, by=k+63, bz=batch); S-tile(y+k, y) = Ea+Eb+Ec elementwise
__global__ __launch_bounds__(256) void band_kernel(const float* __restrict__ E,
                                                   const float* __restrict__ inv,
                                                   u64* __restrict__ packed) {
    __shared__ u64 red[16 * 65];
    int b = blockIdx.z;
    int k = (int)blockIdx.y - 63;
    int t_lo = k < 0 ? -k : 0;
    int t_hi = 64 - (k > 0 ? k : 0);
    int y0 = t_lo + (int)blockIdx.x * 16;
    if (y0 >= t_hi) return;
    int y1 = y0 + 16 < t_hi ? y0 + 16 : t_hi;
    const float* Ebase = E + ((size_t)b << 24);
    const float* invb = inv + b * LPIX;
    u64* pkb = packed + (size_t)b * LPIX;
    int tid = threadIdx.x;
    int c4 = tid & 15, s = tid >> 4;     // cols 4*c4.., x' strata s+16i

    float4 Ea[4], Eb[4], Ec[4];
    auto LOADT = [&](float4* T, int t) {
        if (t >= t_lo && t < t_hi) {
            const float4* tp = (const float4*)(Ebase + ((size_t)(((t + k) << 6) + t) << 12));
#pragma unroll
            for (int i = 0; i < 4; ++i) T[i] = tp[tid + 256 * i];
        } else {
#pragma unroll
            for (int i = 0; i < 4; ++i) T[i] = make_float4(0.f, 0.f, 0.f, 0.f);
        }
    };
    LOADT(Ea, y0 - 1); LOADT(Eb, y0); LOADT(Ec, y0 + 1);

    for (int y = y0; y < y1; ++y) {
        int yprow = (y + k) << 6;        // y' * 64
        u64 kc0 = 0, kc1 = 0, kc2 = 0, kc3 = 0;
#pragma unroll
        for (int i = 0; i < 4; ++i) {
            int xr = s + 16 * i;         // x'
            float iv = invb[yprow + xr];
            int idx = yprow + xr;        // p' = y'*64 + x'
            float vx = (Ea[i].x + Eb[i].x + Ec[i].x) * iv;
            float vy = (Ea[i].y + Eb[i].y + Ec[i].y) * iv;
            float vz = (Ea[i].z + Eb[i].z + Ec[i].z) * iv;
            float vw = (Ea[i].w + Eb[i].w + Ec[i].w) * iv;
            u64 t0 = packKey(vx, idx); kc0 = kc0 > t0 ? kc0 : t0;
            u64 t1 = packKey(vy, idx); kc1 = kc1 > t1 ? kc1 : t1;
            u64 t2 = packKey(vz, idx); kc2 = kc2 > t2 ? kc2 : t2;
            u64 t3 = packKey(vw, idx); kc3 = kc3 > t3 ? kc3 : t3;
        }
        red[s * 65 + 4 * c4 + 0] = kc0;
        red[s * 65 + 4 * c4 + 1] = kc1;
        red[s * 65 + 4 * c4 + 2] = kc2;
        red[s * 65 + 4 * c4 + 3] = kc3;
        __syncthreads();
        if (tid < 64) {
            u64 m = red[tid];
#pragma unroll
            for (int ss = 1; ss < 16; ++ss) {
                u64 v = red[ss * 65 + tid];
                m = m > v ? m : v;
            }
            atomicMax(&pkb[(y << 6) + tid], m);
        }
        __syncthreads();
        if (y + 1 < y1) {
            float4 En[4];
            LOADT(En, y + 2);
#pragma unroll
            for (int i = 0; i < 4; ++i) { Ea[i] = Eb[i]; Eb[i] = Ec[i]; Ec[i] = En[i]; }
        }
    }
}

// ---- gather + fold: one wave per output pixel ----------------------------
__global__ __launch_bounds__(256) void gather_kernel(const u64* __restrict__ packed,
                                                     const float* __restrict__ refT,
                                                     float* __restrict__ Tt) {
    int b = blockIdx.y;
    int wave = threadIdx.x >> 6, lane = threadIdx.x & 63;
    int p = blockIdx.x * 4 + wave;       // 0..4095
    int py = p >> 6, px = p & 63;
    const u64* pk = packed + (size_t)b * LPIX;
    const float* rT = refT + (size_t)b * LPIX * 64;
    float acc = 0.f;
#pragma unroll
    for (int i = 0; i < 3; ++i)
#pragma unroll
        for (int j = 0; j < 3; ++j) {
            int qy = py + 1 - i, qx = px + 1 - j;
            if ((unsigned)qy >= 64u || (unsigned)qx >= 64u) continue;
            int aidx = (int)(~(unsigned int)pk[qy * 64 + qx]);
            int ry = (aidx >> 6) + i - 1, rx = (aidx & 63) + j - 1;
            if ((unsigned)ry >= 64u || (unsigned)rx >= 64u) continue;
            acc += rT[(size_t)(ry * 64 + rx) * 64 + lane];
        }
    Tt[((size_t)b * LPIX + p) * 64 + lane] = acc;
}

// ---- 1x1 conv: z[b][co][p] = w1[co][0:64]*lr + w1[co][64:128]*T + b1 -----
#define XST 36
__global__ __launch_bounds__(256) void conv1_kernel(const float* __restrict__ lr,
                                                    const float* __restrict__ Tt,
                                                    const float* __restrict__ w1,
                                                    const float* __restrict__ b1,
                                                    float* __restrict__ z) {
    __shared__ __align__(16) float xs[128 * XST];
    __shared__ __align__(16) float wsm[64 * 128];
    int pt = blockIdx.x, b = blockIdx.y, tid = threadIdx.x;
    for (int k = 0; k < 8; ++k) {
        int n = tid + 256 * k;           // 2048 float4s of w1
        *(float4*)&wsm[4 * n] = *(const float4*)&w1[4 * n];
    }
    const float* lrb = lr + (size_t)b * CCH * LPIX + pt * 32;
    for (int k = 0; k < 2; ++k) {
        int n = tid + 256 * k;           // 512 f4: c = n>>3, q = n&7
        int c = n >> 3, q = n & 7;
        *(float4*)&xs[c * XST + 4 * q] = *(const float4*)&lrb[(size_t)c * LPIX + 4 * q];
    }
    const float* Tb = Tt + ((size_t)b * LPIX + pt * 32) * 64;
    for (int k = 0; k < 2; ++k) {
        int n = tid + 256 * k;           // 512 f4: p = n>>4, cq = n&15
        int p = n >> 4, cq = n & 15;
        float4 v = *(const float4*)&Tb[p * 64 + 4 * cq];
        xs[(64 + 4 * cq + 0) * XST + p] = v.x;
        xs[(64 + 4 * cq + 1) * XST + p] = v.y;
        xs[(64 + 4 * cq + 2) * XST + p] = v.z;
        xs[(64 + 4 * cq + 3) * XST + p] = v.w;
    }
    __syncthreads();
    int p = tid & 31, g = tid >> 5;      // g: 8 groups of 8 output channels
    float acc[8];
#pragma unroll
    for (int t = 0; t < 8; ++t) acc[t] = b1[g * 8 + t];
    for (int c = 0; c < 128; ++c) {
        float xv = xs[c * XST + p];
#pragma unroll
        for (int t = 0; t < 8; ++t) acc[t] = fmaf(wsm[(g * 8 + t) * 128 + c], xv, acc[t]);
    }
    float* zb = z + (size_t)b * CCH * LPIX + pt * 32;
#pragma unroll
    for (int t = 0; t < 8; ++t) zb[(size_t)(g * 8 + t) * LPIX + p] = acc[t];
}

// ---- depthwise 3x3 + bias + relu -> out ----------------------------------
__global__ __launch_bounds__(256) void dw_kernel(const float* __restrict__ z,
                                                 const float* __restrict__ wd,
                                                 const float* __restrict__ bd,
                                                 float* __restrict__ out) {
    __shared__ __align__(16) float zs[4096];
    int c = blockIdx.x, b = blockIdx.y, tid = threadIdx.x;
    const float* zb = z + ((size_t)b * CCH + c) * LPIX;
    for (int k = 0; k < 4; ++k) {
        int n = tid + 256 * k;
        *(float4*)&zs[4 * n] = *(const float4*)&zb[4 * n];
    }
    __syncthreads();
    float w[9];
#pragma unroll
    for (int t = 0; t < 9; ++t) w[t] = wd[c * 9 + t];
    float bias = bd[c];
    float* ob = out + ((size_t)b * CCH + c) * LPIX;
    for (int s = 0; s < 16; ++s) {
        int p = tid + 256 * s;
        int y = p >> 6, x = p & 63;
        float acc = bias;
#pragma unroll
        for (int i = 0; i < 3; ++i) {
            int yy = y + i - 1;
            if ((unsigned)yy >= 64u) continue;
#pragma unroll
            for (int j = 0; j < 3; ++j) {
                int xx = x + j - 1;
                if ((unsigned)xx >= 64u) continue;
                acc = fmaf(zs[yy * 64 + xx], w[i * 3 + j], acc);
            }
        }
        ob[p] = fmaxf(acc, 0.f);
    }
}

extern "C" void kernel_launch(void* const* d_in, const int* in_sizes, int n_in,
                              void* d_out, int out_size, void* d_ws, size_t ws_size,
                              hipStream_t stream) {
    const float* lr  = (const float*)d_in[0];
    const float* ref = (const float*)d_in[1];
    const float* w1  = (const float*)d_in[2];
    const float* b1  = (const float*)d_in[3];
    const float* wd  = (const float*)d_in[4];
    const float* bd  = (const float*)d_in[5];
    float* out = (float*)d_out;

    float* ws = (float*)d_ws;
    float* refT = ws;                                   // 1,048,576 f
    float* ssq  = refT + (size_t)1048576;               //    16,384 f
    float* inv  = ssq + 16384;                          //    16,384 f
    u64* packed = (u64*)(inv + 16384);                  //    16,384 u64
    float* Tt = (float*)(packed + 16384);               // 1,048,576 f
    float* z  = Tt + (size_t)1048576;                   // 1,048,576 f
    float* E  = z + (size_t)1048576;                    // NB * 16,777,216 f

    const size_t base = 12845056ull;                    // bytes before E
    const size_t per  = 67108864ull;                    // E bytes per batch
    int NB = (ws_size >= base + 4 * per) ? 4 : (ws_size >= base + 2 * per) ? 2 : 1;

    hipMemsetAsync(packed, 0, (size_t)BATCH * LPIX * sizeof(u64), stream);
    prep_kernel<<<dim3(64, BATCH), 256, 0, stream>>>(ref, refT, ssq);
    invnorm_kernel<<<dim3(64), 256, 0, stream>>>(ssq, inv);
    for (int b0 = 0; b0 < BATCH; b0 += NB) {
        gemmE_kernel<<<dim3(32, 32, NB), 256, 0, stream>>>(
            ref + (size_t)b0 * CCH * LPIX, lr + (size_t)b0 * CCH * LPIX, E);
        band_kernel<<<dim3(4, 127, NB), 256, 0, stream>>>(
            E, inv + (size_t)b0 * LPIX, packed + (size_t)b0 * LPIX);
    }
    gather_kernel<<<dim3(1024, BATCH), 256, 0, stream>>>(packed, refT, Tt);
    conv1_kernel<<<dim3(128, BATCH), 256, 0, stream>>>(lr, Tt, w1, b1, z);
    dw_kernel<<<dim3(64, BATCH), 256, 0, stream>>>(z, wd, bd, out);
}

// Round 9
// 259.755 us; speedup vs baseline: 2.9853x; 1.2023x over previous
//
#include <hip/hip_runtime.h>
#include <cstdint>
#include <cstddef>

// SearchTransfer on MI355X (gfx950), fp32.
// B=4, C=64, H=W=64, L=4096, K=9C=576.
//
// Algebra:
//  - lr-patch norm is a positive per-column scalar -> cannot change argmax; dropped.
//  - S[a,b] = sum_{i,j} D[a+d, b+d], D = ref_flat^T * lr_flat (K=64).
//  - E-tile(r1,r2) = x-band of D-tile (register shuffles, R3-validated).
//  - S-tile(y',y) = E(y'-1,y-1)+E(y',y)+E(y'+1,y+1): band kernel streams
//    tile-diagonals with a register ring (R2-validated).
//
// R8 lesson: with NB=4, E (256 MiB) exactly fills the Infinity Cache ->
// thrash; only ~half the E write stream was absorbed (WRITE_SIZE 140 MB of
// 268 MB). v9: NB=2 chunks REUSING one 128 MiB E region -> E always fully
// L3-resident; plain (cache-allocating) stores instead of nt. Arithmetic
// identical -> bit-identical output.

#define BATCH 4
#define CCH 64
#define LPIX 4096
typedef unsigned long long u64;

__device__ __forceinline__ u64 packKey(float v, int idx) {
    unsigned int bits = __float_as_uint(v);
    unsigned int m = (bits & 0x80000000u) ? ~bits : (bits | 0x80000000u);
    // low 32 = ~idx so that larger key == smaller index on equal value
    return ((u64)m << 32) | (unsigned int)(~(unsigned int)idx);
}

// ---- prep: refT[b][p][c] transpose + ssq[b][p] = sum_c ref^2 -------------
__global__ __launch_bounds__(256) void prep_kernel(const float* __restrict__ ref,
                                                   float* __restrict__ refT,
                                                   float* __restrict__ ssq) {
    __shared__ float s[64 * 65];
    __shared__ float part[256];
    int pt = blockIdx.x, b = blockIdx.y, tid = threadIdx.x;
    const float* rb = ref + ((size_t)b * CCH) * LPIX + pt * 64;
    for (int k = 0; k < 16; ++k) {
        int n = tid + 256 * k;           // n = c*64 + p
        int c = n >> 6, p = n & 63;
        s[c * 65 + p] = rb[(size_t)c * LPIX + p];
    }
    __syncthreads();
    {
        int p = tid & 63, g = tid >> 6;
        float acc = 0.f;
        for (int c = g * 16; c < g * 16 + 16; ++c) { float v = s[c * 65 + p]; acc += v * v; }
        part[g * 64 + p] = acc;
    }
    __syncthreads();
    if (tid < 64) {
        float v = part[tid] + part[64 + tid] + part[128 + tid] + part[192 + tid];
        ssq[b * LPIX + pt * 64 + tid] = v;
    }
    float* tb = refT + ((size_t)b * LPIX + pt * 64) * 64;
    for (int k = 0; k < 16; ++k) {
        int n = tid + 256 * k;           // n = p*64 + c
        int p = n >> 6, c = n & 63;
        tb[n] = s[c * 65 + p];
    }
}

// ---- inv[b][p] = 1 / max(sqrt(3x3 box of ssq), 1e-12) --------------------
__global__ __launch_bounds__(256) void invnorm_kernel(const float* __restrict__ ssq,
                                                      float* __restrict__ inv) {
    int t = blockIdx.x * 256 + threadIdx.x;      // over BATCH*LPIX
    int b = t >> 12, p = t & 4095;
    int y = p >> 6, x = p & 63;
    const float* sb = ssq + b * LPIX;
    float n2 = 0.f;
    for (int i = -1; i <= 1; ++i)
        for (int j = -1; j <= 1; ++j) {
            int yy = y + i, xx = x + j;
            if (yy >= 0 && yy < 64 && xx >= 0 && xx < 64) n2 += sb[yy * 64 + xx];
        }
    inv[t] = 1.0f / fmaxf(sqrtf(n2), 1e-12f);
}

// ---- GEMM + x-band epilogue: one wave per 64x64 E-tile (R3-validated) ----
// D[x'][x] = sum_c ref[c,r1,x']*lr[c,r2,x]; E[x'][x] = D[x'-1][x-1]+D[x'][x]+D[x'+1][x+1]
__global__ __launch_bounds__(256, 2) void gemmE_kernel(const float* __restrict__ ref,
                                                       const float* __restrict__ lr,
                                                       float* __restrict__ E) {
    __shared__ __align__(16) float As[2 * 4096];   // [h][c][m], m = x' of tile r1=2by+h
    __shared__ __align__(16) float Bs[2 * 4096];   // [h][c][x], tile r2=2bx+h
    int bx = blockIdx.x, by = blockIdx.y, b = blockIdx.z, tid = threadIdx.x;
    const float* Ab = ref + (size_t)b * CCH * LPIX;
    const float* Bb = lr + (size_t)b * CCH * LPIX;
#pragma unroll
    for (int kk = 0; kk < 8; ++kk) {
        int n = tid + 256 * kk;          // 2048 f4: h = n>>10, c = (n>>4)&63, q = n&15
        int h = n >> 10, c = (n >> 4) & 63, q = n & 15;
        *(float4*)&As[h * 4096 + c * 64 + 4 * q] =
            *(const float4*)&Ab[(size_t)c * LPIX + (2 * by + h) * 64 + 4 * q];
        *(float4*)&Bs[h * 4096 + c * 64 + 4 * q] =
            *(const float4*)&Bb[(size_t)c * LPIX + (2 * bx + h) * 64 + 4 * q];
    }
    __syncthreads();
    int w = tid >> 6, lane = tid & 63, rg = lane >> 3, cg = lane & 7;
    const float* Ap = As + (w >> 1) * 4096 + rg * 8;
    const float* Bp = Bs + (w & 1) * 4096 + cg * 8;
    float acc[8][8] = {};
#pragma unroll 4
    for (int k = 0; k < 64; ++k) {
        float4 a0 = *(const float4*)(Ap + k * 64);
        float4 a1 = *(const float4*)(Ap + k * 64 + 4);
        float4 b0 = *(const float4*)(Bp + k * 64);
        float4 b1 = *(const float4*)(Bp + k * 64 + 4);
        float av[8] = {a0.x, a0.y, a0.z, a0.w, a1.x, a1.y, a1.z, a1.w};
        float bv[8] = {b0.x, b0.y, b0.z, b0.w, b1.x, b1.y, b1.z, b1.w};
#pragma unroll
        for (int i = 0; i < 8; ++i)
#pragma unroll
            for (int j = 0; j < 8; ++j) acc[i][j] = fmaf(av[i], bv[j], acc[i][j]);
    }
    // x-band epilogue in registers: E[r][c] = D[r-1][c-1] + D[r][c] + D[r+1][c+1]
    float up[7], lf[7], dn[8], rt[8], um, dpc;
#pragma unroll
    for (int t = 0; t < 7; ++t) up[t] = __shfl(acc[7][t], lane - 8, 64);
    um = __shfl(acc[7][7], lane - 9, 64);
#pragma unroll
    for (int t = 0; t < 7; ++t) lf[t] = __shfl(acc[t][7], lane - 1, 64);
#pragma unroll
    for (int t = 1; t < 8; ++t) dn[t] = __shfl(acc[0][t], lane + 8, 64);
    dpc = __shfl(acc[0][0], lane + 9, 64);
#pragma unroll
    for (int t = 1; t < 8; ++t) rt[t] = __shfl(acc[t][0], lane + 1, 64);

    int r1 = 2 * by + (w >> 1), r2 = 2 * bx + (w & 1);
    float* Et = E + ((size_t)b << 24) + ((size_t)((r1 << 6) + r2) << 12) + (rg * 8) * 64 + cg * 8;
    bool rgt = rg > 0, rlt = rg < 7, cgt = cg > 0, clt = cg < 7;
#pragma unroll
    for (int i = 0; i < 8; ++i) {
        float e[8];
#pragma unroll
        for (int j = 0; j < 8; ++j) {
            float dm, dpv;
            if (i >= 1) dm = (j >= 1) ? acc[i - 1][j - 1] : (cgt ? lf[i - 1] : 0.f);
            else        dm = rgt ? ((j >= 1) ? up[j - 1] : (cgt ? um : 0.f)) : 0.f;
            if (i <= 6) dpv = (j <= 6) ? acc[i + 1][j + 1] : (clt ? rt[i + 1] : 0.f);
            else        dpv = rlt ? ((j <= 6) ? dn[j + 1] : (clt ? dpc : 0.f)) : 0.f;
            e[j] = dm + acc[i][j] + dpv;
        }
        *(float4*)(Et + i * 64)     = make_float4(e[0], e[1], e[2], e[3]);
        *(float4*)(Et + i * 64 + 4) = make_float4(e[4], e[5], e[6], e[7]);
    }
}

// ---- band: diagonal-segment sweep, register ring of 3 E-tiles (R2) -------
// block (bx=segment, by=k+63, bz=batch); S-tile(y+k, y) = Ea+Eb+Ec elementwise
__global__ __launch_bounds__(256) void band_kernel(const float* __restrict__ E,
                                                   const float* __restrict__ inv,
                                                   u64* __restrict__ packed) {
    __shared__ u64 red[16 * 65];
    int b = blockIdx.z;
    int k = (int)blockIdx.y - 63;
    int t_lo = k < 0 ? -k : 0;
    int t_hi = 64 - (k > 0 ? k : 0);
    int y0 = t_lo + (int)blockIdx.x * 16;
    if (y0 >= t_hi) return;
    int y1 = y0 + 16 < t_hi ? y0 + 16 : t_hi;
    const float* Ebase = E + ((size_t)b << 24);
    const float* invb = inv + b * LPIX;
    u64* pkb = packed + (size_t)b * LPIX;
    int tid = threadIdx.x;
    int c4 = tid & 15, s = tid >> 4;     // cols 4*c4.., x' strata s+16i

    float4 Ea[4], Eb[4], Ec[4];
    auto LOADT = [&](float4* T, int t) {
        if (t >= t_lo && t < t_hi) {
            const float4* tp = (const float4*)(Ebase + ((size_t)(((t + k) << 6) + t) << 12));
#pragma unroll
            for (int i = 0; i < 4; ++i) T[i] = tp[tid + 256 * i];
        } else {
#pragma unroll
            for (int i = 0; i < 4; ++i) T[i] = make_float4(0.f, 0.f, 0.f, 0.f);
        }
    };
    LOADT(Ea, y0 - 1); LOADT(Eb, y0); LOADT(Ec, y0 + 1);

    for (int y = y0; y < y1; ++y) {
        int yprow = (y + k) << 6;        // y' * 64
        u64 kc0 = 0, kc1 = 0, kc2 = 0, kc3 = 0;
#pragma unroll
        for (int i = 0; i < 4; ++i) {
            int xr = s + 16 * i;         // x'
            float iv = invb[yprow + xr];
            int idx = yprow + xr;        // p' = y'*64 + x'
            float vx = (Ea[i].x + Eb[i].x + Ec[i].x) * iv;
            float vy = (Ea[i].y + Eb[i].y + Ec[i].y) * iv;
            float vz = (Ea[i].z + Eb[i].z + Ec[i].z) * iv;
            float vw = (Ea[i].w + Eb[i].w + Ec[i].w) * iv;
            u64 t0 = packKey(vx, idx); kc0 = kc0 > t0 ? kc0 : t0;
            u64 t1 = packKey(vy, idx); kc1 = kc1 > t1 ? kc1 : t1;
            u64 t2 = packKey(vz, idx); kc2 = kc2 > t2 ? kc2 : t2;
            u64 t3 = packKey(vw, idx); kc3 = kc3 > t3 ? kc3 : t3;
        }
        red[s * 65 + 4 * c4 + 0] = kc0;
        red[s * 65 + 4 * c4 + 1] = kc1;
        red[s * 65 + 4 * c4 + 2] = kc2;
        red[s * 65 + 4 * c4 + 3] = kc3;
        __syncthreads();
        if (tid < 64) {
            u64 m = red[tid];
#pragma unroll
            for (int ss = 1; ss < 16; ++ss) {
                u64 v = red[ss * 65 + tid];
                m = m > v ? m : v;
            }
            atomicMax(&pkb[(y << 6) + tid], m);
        }
        __syncthreads();
        if (y + 1 < y1) {
            float4 En[4];
            LOADT(En, y + 2);
#pragma unroll
            for (int i = 0; i < 4; ++i) { Ea[i] = Eb[i]; Eb[i] = Ec[i]; Ec[i] = En[i]; }
        }
    }
}

// ---- gather + fold: one wave per output pixel ----------------------------
__global__ __launch_bounds__(256) void gather_kernel(const u64* __restrict__ packed,
                                                     const float* __restrict__ refT,
                                                     float* __restrict__ Tt) {
    int b = blockIdx.y;
    int wave = threadIdx.x >> 6, lane = threadIdx.x & 63;
    int p = blockIdx.x * 4 + wave;       // 0..4095
    int py = p >> 6, px = p & 63;
    const u64* pk = packed + (size_t)b * LPIX;
    const float* rT = refT + (size_t)b * LPIX * 64;
    float acc = 0.f;
#pragma unroll
    for (int i = 0; i < 3; ++i)
#pragma unroll
        for (int j = 0; j < 3; ++j) {
            int qy = py + 1 - i, qx = px + 1 - j;
            if ((unsigned)qy >= 64u || (unsigned)qx >= 64u) continue;
            int aidx = (int)(~(unsigned int)pk[qy * 64 + qx]);
            int ry = (aidx >> 6) + i - 1, rx = (aidx & 63) + j - 1;
            if ((unsigned)ry >= 64u || (unsigned)rx >= 64u) continue;
            acc += rT[(size_t)(ry * 64 + rx) * 64 + lane];
        }
    Tt[((size_t)b * LPIX + p) * 64 + lane] = acc;
}

// ---- 1x1 conv: z[b][co][p] = w1[co][0:64]*lr + w1[co][64:128]*T + b1 -----
#define XST 36
__global__ __launch_bounds__(256) void conv1_kernel(const float* __restrict__ lr,
                                                    const float* __restrict__ Tt,
                                                    const float* __restrict__ w1,
                                                    const float* __restrict__ b1,
                                                    float* __restrict__ z) {
    __shared__ __align__(16) float xs[128 * XST];
    __shared__ __align__(16) float wsm[64 * 128];
    int pt = blockIdx.x, b = blockIdx.y, tid = threadIdx.x;
    for (int k = 0; k < 8; ++k) {
        int n = tid + 256 * k;           // 2048 float4s of w1
        *(float4*)&wsm[4 * n] = *(const float4*)&w1[4 * n];
    }
    const float* lrb = lr + (size_t)b * CCH * LPIX + pt * 32;
    for (int k = 0; k < 2; ++k) {
        int n = tid + 256 * k;           // 512 f4: c = n>>3, q = n&7
        int c = n >> 3, q = n & 7;
        *(float4*)&xs[c * XST + 4 * q] = *(const float4*)&lrb[(size_t)c * LPIX + 4 * q];
    }
    const float* Tb = Tt + ((size_t)b * LPIX + pt * 32) * 64;
    for (int k = 0; k < 2; ++k) {
        int n = tid + 256 * k;           // 512 f4: p = n>>4, cq = n&15
        int p = n >> 4, cq = n & 15;
        float4 v = *(const float4*)&Tb[p * 64 + 4 * cq];
        xs[(64 + 4 * cq + 0) * XST + p] = v.x;
        xs[(64 + 4 * cq + 1) * XST + p] = v.y;
        xs[(64 + 4 * cq + 2) * XST + p] = v.z;
        xs[(64 + 4 * cq + 3) * XST + p] = v.w;
    }
    __syncthreads();
    int p = tid & 31, g = tid >> 5;      // g: 8 groups of 8 output channels
    float acc[8];
#pragma unroll
    for (int t = 0; t < 8; ++t) acc[t] = b1[g * 8 + t];
    for (int c = 0; c < 128; ++c) {
        float xv = xs[c * XST + p];
#pragma unroll
        for (int t = 0; t < 8; ++t) acc[t] = fmaf(wsm[(g * 8 + t) * 128 + c], xv, acc[t]);
    }
    float* zb = z + (size_t)b * CCH * LPIX + pt * 32;
#pragma unroll
    for (int t = 0; t < 8; ++t) zb[(size_t)(g * 8 + t) * LPIX + p] = acc[t];
}

// ---- depthwise 3x3 + bias + relu -> out ----------------------------------
__global__ __launch_bounds__(256) void dw_kernel(const float* __restrict__ z,
                                                 const float* __restrict__ wd,
                                                 const float* __restrict__ bd,
                                                 float* __restrict__ out) {
    __shared__ __align__(16) float zs[4096];
    int c = blockIdx.x, b = blockIdx.y, tid = threadIdx.x;
    const float* zb = z + ((size_t)b * CCH + c) * LPIX;
    for (int k = 0; k < 4; ++k) {
        int n = tid + 256 * k;
        *(float4*)&zs[4 * n] = *(const float4*)&zb[4 * n];
    }
    __syncthreads();
    float w[9];
#pragma unroll
    for (int t = 0; t < 9; ++t) w[t] = wd[c * 9 + t];
    float bias = bd[c];
    float* ob = out + ((size_t)b * CCH + c) * LPIX;
    for (int s = 0; s < 16; ++s) {
        int p = tid + 256 * s;
        int y = p >> 6, x = p & 63;
        float acc = bias;
#pragma unroll
        for (int i = 0; i < 3; ++i) {
            int yy = y + i - 1;
            if ((unsigned)yy >= 64u) continue;
#pragma unroll
            for (int j = 0; j < 3; ++j) {
                int xx = x + j - 1;
                if ((unsigned)xx >= 64u) continue;
                acc = fmaf(zs[yy * 64 + xx], w[i * 3 + j], acc);
            }
        }
        ob[p] = fmaxf(acc, 0.f);
    }
}

extern "C" void kernel_launch(void* const* d_in, const int* in_sizes, int n_in,
                              void* d_out, int out_size, void* d_ws, size_t ws_size,
                              hipStream_t stream) {
    const float* lr  = (const float*)d_in[0];
    const float* ref = (const float*)d_in[1];
    const float* w1  = (const float*)d_in[2];
    const float* b1  = (const float*)d_in[3];
    const float* wd  = (const float*)d_in[4];
    const float* bd  = (const float*)d_in[5];
    float* out = (float*)d_out;

    float* ws = (float*)d_ws;
    float* refT = ws;                                   // 1,048,576 f
    float* ssq  = refT + (size_t)1048576;               //    16,384 f
    float* inv  = ssq + 16384;                          //    16,384 f
    u64* packed = (u64*)(inv + 16384);                  //    16,384 u64
    float* Tt = (float*)(packed + 16384);               // 1,048,576 f
    float* z  = Tt + (size_t)1048576;                   // 1,048,576 f
    float* E  = z + (size_t)1048576;                    // NB * 16,777,216 f (reused)

    const size_t base = 12845056ull;                    // bytes before E
    const size_t per  = 67108864ull;                    // E bytes per batch
    // NB=2 keeps live E at 128 MiB -> fully Infinity-Cache-resident (256 MiB L3).
    int NB = (ws_size >= base + 2 * per) ? 2 : 1;

    hipMemsetAsync(packed, 0, (size_t)BATCH * LPIX * sizeof(u64), stream);
    prep_kernel<<<dim3(64, BATCH), 256, 0, stream>>>(ref, refT, ssq);
    invnorm_kernel<<<dim3(64), 256, 0, stream>>>(ssq, inv);
    for (int b0 = 0; b0 < BATCH; b0 += NB) {
        gemmE_kernel<<<dim3(32, 32, NB), 256, 0, stream>>>(
            ref + (size_t)b0 * CCH * LPIX, lr + (size_t)b0 * CCH * LPIX, E);
        band_kernel<<<dim3(4, 127, NB), 256, 0, stream>>>(
            E, inv + (size_t)b0 * LPIX, packed + (size_t)b0 * LPIX);
    }
    gather_kernel<<<dim3(1024, BATCH), 256, 0, stream>>>(packed, refT, Tt);
    conv1_kernel<<<dim3(128, BATCH), 256, 0, stream>>>(lr, Tt, w1, b1, z);
    dw_kernel<<<dim3(64, BATCH), 256, 0, stream>>>(z, wd, bd, out);
}